// Round 1
// 128.637 us; speedup vs baseline: 1.0827x; 1.0827x over previous
//
#include <hip/hip_runtime.h>

// GCNConv: out = D^-1/2 (A + I) D^-1/2 (x W) + bias
// N = 10000, E = 640000, D_IN = D_OUT = 128, fp32 in/out.
//
// Round 8: gather width rebalance. 16 lanes/edge (uint4 = 8 bf16 per lane),
// 4 edges per wave-step -> half the loop steps, half the shfl/load
// instructions, shorter acc dependency chains. Butterfly fold (^32, ^16)
// leaves full sums in all lanes; lanes 0..31 write one coalesced float4 each.
// Also: float4-vectorized x-tile staging in the gemm phase.
//
//  K1 hist (64 blocks x 1024): packed LDS histogram (out low16 | in high16),
//     rank[e] = per-(block,c) in-rank (ushort). partial = 2.56 MB only.
//  K2 reduce: per node: dis = rsqrt(1+outdeg); 64-deep exclusive prefix of
//     per-block in-counts (suboff, in place); indeg totals.
//  K3 fillgemm (fused): blocks 0..63 fill csr_src (USHORT src ids) at
//     slot = c*256 + suboff[b][c] + rank[e]; blocks 64.. do
//     g = bf16(x @ W * dis[row])  (32 rows/block).
//  K4 gather: wave/node, quarter-wave = 4 edges/step, lane reads uint4
//     (8 bf16) of g; fp32 accumulate; out = dis[c]*(sum + g[c]) + bias.

#define NNODES 10000
#define NB 64            // histogram / fill blocks
#define CAP 256          // CSR slots per node
#define HBLOCK 1024

__device__ inline unsigned short f2bf(float f) {
    union { float f; unsigned u; } v; v.f = f;
    unsigned r = v.u + 0x7FFFu + ((v.u >> 16) & 1u);   // RNE
    return (unsigned short)(r >> 16);
}
__device__ inline float bf2f_lo(unsigned u) {   // low ushort of dword -> f32
    union { unsigned u; float f; } v; v.u = u << 16; return v.f;
}
__device__ inline float bf2f_hi(unsigned u) {   // high ushort of dword -> f32
    union { unsigned u; float f; } v; v.u = u & 0xFFFF0000u; return v.f;
}

__global__ __launch_bounds__(HBLOCK) void hist_kernel(
    const int* __restrict__ row, const int* __restrict__ col,
    int* __restrict__ partial, unsigned short* __restrict__ rank,
    int N, int E, int EPB) {
    __shared__ int hmem[NNODES];
    const int tid = threadIdx.x, b = blockIdx.x;
    for (int j = tid; j < N; j += HBLOCK) hmem[j] = 0;
    __syncthreads();
    const int e0 = b * EPB, e1 = min(E, e0 + EPB);
    for (int e = e0 + tid; e < e1; e += HBLOCK) {
        int r = row[e], c = col[e];
        atomicAdd(&hmem[r], 1);                                   // out-deg lo16
        unsigned old = atomicAdd((unsigned*)&hmem[c], 0x10000u);  // in-deg hi16
        rank[e] = (unsigned short)(old >> 16);
    }
    __syncthreads();
    for (int j = tid; j < N; j += HBLOCK) partial[b * N + j] = hmem[j];
}

__global__ void reduce_kernel(int* __restrict__ partial, float* __restrict__ dis,
                              int* __restrict__ indeg, int N) {
    int n = blockIdx.x * blockDim.x + threadIdx.x;   // coalesced in n
    if (n >= N) return;
    int s = 0, run = 0;
#pragma unroll 8
    for (int b = 0; b < NB; ++b) {
        int v = partial[b * N + n];
        s += v & 0xFFFF;
        partial[b * N + n] = run;                    // becomes suboff[b][n]
        run += ((unsigned)v) >> 16;
    }
    dis[n] = rsqrtf(1.0f + (float)s);
    indeg[n] = run;
}

__global__ __launch_bounds__(HBLOCK) void fillgemm_kernel(
    const int* __restrict__ row, const int* __restrict__ col,
    const int* __restrict__ partial, const unsigned short* __restrict__ rank,
    const float* __restrict__ dis, unsigned short* __restrict__ csr_src,
    const float* __restrict__ x, const float* __restrict__ W,
    unsigned short* __restrict__ g, int N, int E, int EPB) {
    __shared__ int lds[NNODES];     // fill: base table; gemm: reuses as x-tile
    const int tid = threadIdx.x;

    if (blockIdx.x < NB) {
        // ---- fill: atomic-free CSR scatter (ushort src ids) ----
        const int b = blockIdx.x;
        for (int j = tid; j < N; j += HBLOCK)
            lds[j] = (j << 8) + partial[b * N + j];   // c*CAP + suboff[b][c]
        __syncthreads();
        const int e0 = b * EPB, e1 = min(E, e0 + EPB);
        for (int e = e0 + tid; e < e1; e += HBLOCK)
            csr_src[lds[col[e]] + (int)rank[e]] = (unsigned short)row[e];
    } else {
        // ---- gemm: g = bf16((x @ W) * dis[row]), 32 rows/block ----
        float* xs = (float*)lds;                       // 32*128*4 = 16 KB
        const int rowBase = (blockIdx.x - NB) * 32;
        {
            // 1024 threads x float4 = exactly the 32x128 tile
            int r = rowBase + (tid >> 5);
            float4 v = make_float4(0.f, 0.f, 0.f, 0.f);
            if (r < N) v = ((const float4*)x)[rowBase * 32 + tid];
            ((float4*)xs)[tid] = v;
        }
        __syncthreads();
        const int lr = tid >> 5, c4 = tid & 31;
        const int rr = rowBase + lr;
        const float4* __restrict__ W4 = (const float4*)W;
        float4 acc = make_float4(0.f, 0.f, 0.f, 0.f);
#pragma unroll 8
        for (int k = 0; k < 128; ++k) {
            float xv = xs[lr * 128 + k];
            float4 wv = W4[k * 32 + c4];
            acc.x = fmaf(xv, wv.x, acc.x);
            acc.y = fmaf(xv, wv.y, acc.y);
            acc.z = fmaf(xv, wv.z, acc.z);
            acc.w = fmaf(xv, wv.w, acc.w);
        }
        if (rr < N) {
            float d = dis[rr];
            ushort4 o;
            o.x = f2bf(acc.x * d);
            o.y = f2bf(acc.y * d);
            o.z = f2bf(acc.z * d);
            o.w = f2bf(acc.w * d);
            ((ushort4*)g)[rr * 32 + c4] = o;
        }
    }
}

// One wave per destination node. q = lane>>4 picks one of 4 edges per step;
// l16 = lane&15 picks the 16B chunk (16 x 16B = one 256B bf16 row of g).
// Accumulate lo/hi bf16 halves of each dword separately in fp32.
__global__ void gather_kernel(const int* __restrict__ indeg,
                              const unsigned short* __restrict__ csr_src,
                              const unsigned short* __restrict__ g,
                              const float* __restrict__ dis,
                              const float* __restrict__ bias,
                              float* __restrict__ out, int n) {
    const int wave = (blockIdx.x * blockDim.x + threadIdx.x) >> 6;
    const int lane = threadIdx.x & 63;
    if (wave >= n) return;
    const int c = wave;
    const int q = lane >> 4;      // edge sub-slot within a 4-edge step
    const int l16 = lane & 15;    // 16B chunk within the 256B row
    const uint4* __restrict__ g4 = (const uint4*)g;

    float al0 = 0.f, ah0 = 0.f, al1 = 0.f, ah1 = 0.f;
    float al2 = 0.f, ah2 = 0.f, al3 = 0.f, ah3 = 0.f;

    if (q == 0) {   // self-loop term: + g[c] (counted once)
        uint4 w = g4[c * 16 + l16];
        al0 += bf2f_lo(w.x); ah0 += bf2f_hi(w.x);
        al1 += bf2f_lo(w.y); ah1 += bf2f_hi(w.y);
        al2 += bf2f_lo(w.z); ah2 += bf2f_hi(w.z);
        al3 += bf2f_lo(w.w); ah3 += bf2f_hi(w.w);
    }

    const int start = c << 8;              // c * CAP
    const int end = start + indeg[c];
    for (int base = start; base < end; base += 64) {
        int idx = base + lane;
        int src = (idx < end) ? (int)csr_src[idx] : 0;
        int cnt = min(64, end - base);
#pragma unroll
        for (int t = 0; t < 64; t += 4) {
            int j = t + q;                 // quarter q handles edge t+q
            int r = __shfl(src, j);
            if (j < cnt) {
                uint4 w = g4[r * 16 + l16];
                al0 += bf2f_lo(w.x); ah0 += bf2f_hi(w.x);
                al1 += bf2f_lo(w.y); ah1 += bf2f_hi(w.y);
                al2 += bf2f_lo(w.z); ah2 += bf2f_hi(w.z);
                al3 += bf2f_lo(w.w); ah3 += bf2f_hi(w.w);
            }
        }
    }
    // Butterfly over the quarter bits (lane bits 5,4): every lane ends with
    // the full sum for its l16 chunk.
    al0 += __shfl(al0, lane ^ 32); ah0 += __shfl(ah0, lane ^ 32);
    al1 += __shfl(al1, lane ^ 32); ah1 += __shfl(ah1, lane ^ 32);
    al2 += __shfl(al2, lane ^ 32); ah2 += __shfl(ah2, lane ^ 32);
    al3 += __shfl(al3, lane ^ 32); ah3 += __shfl(ah3, lane ^ 32);
    al0 += __shfl(al0, lane ^ 16); ah0 += __shfl(ah0, lane ^ 16);
    al1 += __shfl(al1, lane ^ 16); ah1 += __shfl(ah1, lane ^ 16);
    al2 += __shfl(al2, lane ^ 16); ah2 += __shfl(ah2, lane ^ 16);
    al3 += __shfl(al3, lane ^ 16); ah3 += __shfl(ah3, lane ^ 16);

    if (lane < 32) {
        // lane l<16 writes cols l*8..l*8+3 (dwords 0,1);
        // lane l+16 writes cols l*8+4..l*8+7 (dwords 2,3).
        float dc = dis[c];
        int oi = ((lane & 15) << 1) | (lane >> 4);   // float4 slot 0..31
        float4 bv = ((const float4*)bias)[oi];
        float4 o;
        if (lane < 16) {
            o.x = fmaf(al0, dc, bv.x);
            o.y = fmaf(ah0, dc, bv.y);
            o.z = fmaf(al1, dc, bv.z);
            o.w = fmaf(ah1, dc, bv.w);
        } else {
            o.x = fmaf(al2, dc, bv.x);
            o.y = fmaf(ah2, dc, bv.y);
            o.z = fmaf(al3, dc, bv.z);
            o.w = fmaf(ah3, dc, bv.w);
        }
        ((float4*)out)[c * 32 + oi] = o;
    }
}

extern "C" void kernel_launch(void* const* d_in, const int* in_sizes, int n_in,
                              void* d_out, int out_size, void* d_ws, size_t ws_size,
                              hipStream_t stream) {
    const float* x    = (const float*)d_in[0];
    const int*   ei   = (const int*)d_in[1];
    const float* W    = (const float*)d_in[2];
    const float* bias = (const float*)d_in[3];
    float* out = (float*)d_out;

    int N = in_sizes[0] / 128;     // 10000
    int E = in_sizes[1] / 2;       // 640000
    const int* row = ei;
    const int* col = ei + E;
    int EPB = (E + NB - 1) / NB;   // 10000

    // Workspace (~9.5 MB):
    auto align256 = [](size_t v) { return (v + 255) & ~(size_t)255; };
    char* p = (char*)d_ws;
    int*            partial = (int*)p;            p += align256((size_t)NB * N * 4);   // 2.56 MB
    unsigned short* rank    = (unsigned short*)p; p += align256((size_t)E * 2);        // 1.28 MB
    float*          dis     = (float*)p;          p += align256((size_t)N * 4);
    int*            indeg   = (int*)p;            p += align256((size_t)N * 4);
    unsigned short* csr_src = (unsigned short*)p; p += align256((size_t)N * CAP * 2);  // 5.12 MB
    unsigned short* g       = (unsigned short*)p; p += align256((size_t)N * 128 * 2);  // 2.56 MB

    hist_kernel<<<NB, HBLOCK, 0, stream>>>(row, col, partial, rank, N, E, EPB);
    reduce_kernel<<<(N + 255) / 256, 256, 0, stream>>>(partial, dis, indeg, N);

    int gemmBlocks = (N + 31) / 32;  // 313
    fillgemm_kernel<<<NB + gemmBlocks, HBLOCK, 0, stream>>>(
        row, col, partial, rank, dis, csr_src, x, W, g, N, E, EPB);

    long long gthreads = (long long)N * 64;
    gather_kernel<<<(int)((gthreads + 255) / 256), 256, 0, stream>>>(
        indeg, csr_src, g, dis, bias, out, N);
}